// Round 6
// baseline (653.354 us; speedup 1.0000x reference)
//
#include <hip/hip_runtime.h>
#include <math.h>

#define NB 16

// ---------------- shapes ----------------
// x:      (16, 3,16,128,128)
// y1:     (16, 4, 8, 64, 64)   conv1 k4 s2 p1 + relu
// y2:     (16, 8, 4, 32, 32)   conv2 k4 s2 p1 + relu
// z:      (16,16, 4, 32, 32)   conv4 k3 s1 p1 + clip(0,6)
// quant:  (16,16, 4, 32, 32)   VQ
// d1:     (16, 8, 8, 64, 64)   deconv1 k4 s2 p1 + relu
// d2:     (16, 4,16,128,128)   deconv3 k4 s2 p1 + relu
// out:    (16, 3,16,128,128)   deconv4 k3 s1 p1

__device__ __forceinline__ float4 ld4(const float* p) {
  return *reinterpret_cast<const float4*>(p);
}
__device__ __forceinline__ void st4(float* p, float4 v) {
  *reinterpret_cast<float4*>(p) = v;
}

// conv1 (unchanged from R4): thread = 4 co x (1 od, 1 oh, 4 ow). 512 blocks.
__global__ __launch_bounds__(256) void conv1_k(
    const float* __restrict__ x, const float* __restrict__ w,
    const float* __restrict__ bias, float* __restrict__ y) {
  int idx = blockIdx.x * 256 + threadIdx.x;
  int g  = idx & 15;
  int oh = (idx >> 4) & 63;
  int od = (idx >> 10) & 7;
  int n  = idx >> 13;
  bool gl = (g > 0), gr = (g < 15);
  float acc[4][4];
  #pragma unroll
  for (int co = 0; co < 4; co++) {
    float bv = bias[co];
    #pragma unroll
    for (int m = 0; m < 4; m++) acc[co][m] = bv;
  }
  int ih0 = 2 * oh - 1;
  #pragma unroll 1
  for (int ci = 0; ci < 3; ci++) {
    #pragma unroll 1
    for (int kd = 0; kd < 4; kd++) {
      int id = 2 * od - 1 + kd;
      bool vd = (unsigned)id < 16u;
      int idc = vd ? id : 0;
      const float* plane = x + (((n * 3 + ci) * 16 + idc) * 16384);
      #pragma unroll
      for (int kh = 0; kh < 4; kh++) {
        int ih = ih0 + kh;
        bool v = vd && ((unsigned)ih < 128u);
        int ihc = (unsigned)ih < 128u ? ih : 0;
        const float* rp = plane + ihc * 128 + 8 * g;
        float r[10];
        float4 A = ld4(rp);
        float4 B = ld4(rp + 4);
        float rl = rp[-1 * (int)gl];
        float rr = rp[gr ? 8 : 0];
        r[0] = (v && gl) ? rl : 0.0f;
        r[1] = v ? A.x : 0.0f; r[2] = v ? A.y : 0.0f;
        r[3] = v ? A.z : 0.0f; r[4] = v ? A.w : 0.0f;
        r[5] = v ? B.x : 0.0f; r[6] = v ? B.y : 0.0f;
        r[7] = v ? B.z : 0.0f; r[8] = v ? B.w : 0.0f;
        r[9] = (v && gr) ? rr : 0.0f;
        #pragma unroll
        for (int co = 0; co < 4; co++) {
          const float* wb = w + ((co * 3 + ci) * 4 + kd) * 16 + kh * 4;
          #pragma unroll
          for (int kw = 0; kw < 4; kw++) {
            float wv = wb[kw];
            #pragma unroll
            for (int m = 0; m < 4; m++)
              acc[co][m] += r[2 * m + kw] * wv;
          }
        }
      }
    }
  }
  #pragma unroll
  for (int co = 0; co < 4; co++) {
    float4 o;
    o.x = fmaxf(acc[co][0], 0.0f); o.y = fmaxf(acc[co][1], 0.0f);
    o.z = fmaxf(acc[co][2], 0.0f); o.w = fmaxf(acc[co][3], 0.0f);
    st4(y + ((n * 4 + co) * 8 + od) * 4096 + oh * 64 + 4 * g, o);
  }
}

// conv2 (unchanged): thread = 1 pos x 4 co. 512 blocks.
__global__ __launch_bounds__(256) void conv2_k(
    const float* __restrict__ y1, const float* __restrict__ w,
    const float* __restrict__ bias, float* __restrict__ y) {
  int idx = blockIdx.x * 256 + threadIdx.x;
  int ow = idx & 31;
  int oh = (idx >> 5) & 31;
  int od = (idx >> 10) & 3;
  int n = (idx >> 12) & 15;
  int cog = idx >> 16;
  float acc[4];
  #pragma unroll
  for (int co = 0; co < 4; co++) acc[co] = bias[cog * 4 + co];
  int id0 = 2 * od - 1, ih0 = 2 * oh - 1, iw0 = 2 * ow - 1;
  bool vh[4], vw[4];
  #pragma unroll
  for (int l = 0; l < 4; l++) {
    vh[l] = (unsigned)(ih0 + l) < 64u;
    vw[l] = (unsigned)(iw0 + l) < 64u;
  }
  #pragma unroll 1
  for (int ci = 0; ci < 4; ci++) {
    const float* ip = y1 + ((n * 4 + ci) * 8) * 4096;
    #pragma unroll
    for (int kd = 0; kd < 4; kd++) {
      int id = id0 + kd;
      bool vd = (unsigned)id < 8u;
      const float* pp = ip + id * 4096;
      float p[4][4];
      #pragma unroll
      for (int kh = 0; kh < 4; kh++)
        #pragma unroll
        for (int kw = 0; kw < 4; kw++)
          p[kh][kw] = (vd && vh[kh] && vw[kw]) ? pp[(ih0 + kh) * 64 + (iw0 + kw)] : 0.0f;
      #pragma unroll
      for (int co = 0; co < 4; co++) {
        const float* wp = w + (((cog * 4 + co) * 4 + ci) * 4 + kd) * 16;
        #pragma unroll
        for (int kh = 0; kh < 4; kh++)
          #pragma unroll
          for (int kw = 0; kw < 4; kw++)
            acc[co] += p[kh][kw] * wp[kh * 4 + kw];
      }
    }
  }
  #pragma unroll
  for (int co = 0; co < 4; co++)
    y[((n * 8 + cog * 4 + co) * 4 + od) * 1024 + oh * 32 + ow] = fmaxf(acc[co], 0.0f);
}

// conv4 (unchanged): thread = 1 pos x 4 co. 1024 blocks.
__global__ __launch_bounds__(256) void conv4_k(
    const float* __restrict__ y2, const float* __restrict__ w,
    const float* __restrict__ bias, float* __restrict__ z) {
  int idx = blockIdx.x * 256 + threadIdx.x;
  int ow = idx & 31;
  int oh = (idx >> 5) & 31;
  int od = (idx >> 10) & 3;
  int n = (idx >> 12) & 15;
  int cog = idx >> 16;
  float acc[4];
  #pragma unroll
  for (int co = 0; co < 4; co++) acc[co] = bias[cog * 4 + co];
  bool vh[3], vw[3];
  #pragma unroll
  for (int l = 0; l < 3; l++) {
    vh[l] = (unsigned)(oh - 1 + l) < 32u;
    vw[l] = (unsigned)(ow - 1 + l) < 32u;
  }
  #pragma unroll 1
  for (int ci = 0; ci < 8; ci++) {
    const float* ip = y2 + ((n * 8 + ci) * 4) * 1024;
    #pragma unroll
    for (int kd = 0; kd < 3; kd++) {
      int id = od - 1 + kd;
      bool vd = (unsigned)id < 4u;
      const float* pp = ip + id * 1024;
      float p[3][3];
      #pragma unroll
      for (int kh = 0; kh < 3; kh++)
        #pragma unroll
        for (int kw = 0; kw < 3; kw++)
          p[kh][kw] = (vd && vh[kh] && vw[kw]) ? pp[(oh - 1 + kh) * 32 + (ow - 1 + kw)] : 0.0f;
      #pragma unroll
      for (int co = 0; co < 4; co++) {
        const float* wp = w + (((cog * 4 + co) * 8 + ci) * 3 + kd) * 9;
        #pragma unroll
        for (int kh = 0; kh < 3; kh++)
          #pragma unroll
          for (int kw = 0; kw < 3; kw++)
            acc[co] += p[kh][kw] * wp[kh * 3 + kw];
      }
    }
  }
  #pragma unroll
  for (int co = 0; co < 4; co++)
    z[((n * 16 + cog * 4 + co) * 4 + od) * 1024 + oh * 32 + ow] =
        fminf(fmaxf(acc[co], 0.0f), 6.0f);
}

// VQ (unchanged)
__global__ __launch_bounds__(256) void vq_k(
    const float* __restrict__ z, const float* __restrict__ emb,
    float* __restrict__ quant, float* __restrict__ codes_out,
    float* __restrict__ stats) {
  __shared__ float se[32 * 16];
  __shared__ float se2[32];
  __shared__ float shist[32];
  __shared__ float swred[4];
  int tid = threadIdx.x;
  for (int i = tid; i < 512; i += 256) {
    int r = i >> 4;
    float v = emb[i];
    if (r == 0) v = 0.0f;
    else if (r == 1) v = 6.0f;
    se[i] = v;
  }
  if (tid < 32) shist[tid] = 0.0f;
  __syncthreads();
  if (tid < 32) {
    float s = 0.0f;
    #pragma unroll
    for (int d = 0; d < 16; d++) { float v = se[tid * 16 + d]; s += v * v; }
    se2[tid] = s;
  }
  __syncthreads();

  int idx = blockIdx.x * 256 + tid;
  float lsum = 0.0f;
  {
    int w_ = idx & 31; int t = idx >> 5;
    int h_ = t & 31; t >>= 5;
    int d_ = t & 3;  int b_ = t >> 2;
    const float* zp = z + b_ * 65536 + d_ * 1024 + h_ * 32 + w_;
    float f[16];
    float f2 = 0.0f;
    #pragma unroll
    for (int c = 0; c < 16; c++) { float v = zp[c * 4096]; f[c] = v; f2 += v * v; }
    float best = 1e30f; int bi = 0;
    for (int e = 0; e < 32; e++) {
      float dot = 0.0f;
      #pragma unroll
      for (int c = 0; c < 16; c++) dot += f[c] * se[e * 16 + c];
      float d2 = f2 - 2.0f * dot + se2[e];
      if (d2 < best) { best = d2; bi = e; }
    }
    float* qp = quant + b_ * 65536 + d_ * 1024 + h_ * 32 + w_;
    #pragma unroll
    for (int c = 0; c < 16; c++) {
      float q = se[bi * 16 + c];
      qp[c * 4096] = q;
      float df = q - f[c];
      lsum += df * df;
    }
    codes_out[idx] = (float)bi;
    atomicAdd(&shist[bi], 1.0f);
  }
  for (int o = 32; o; o >>= 1) lsum += __shfl_down(lsum, o);
  if ((tid & 63) == 0) swred[tid >> 6] = lsum;
  __syncthreads();
  if (tid == 0) atomicAdd(&stats[0], swred[0] + swred[1] + swred[2] + swred[3]);
  if (tid < 32) {
    float h = shist[tid];
    if (h != 0.0f) atomicAdd(&stats[1 + tid], h);
  }
}

__global__ void init_stats_k(float* __restrict__ stats) {
  int tid = threadIdx.x;
  if (tid < 33) stats[tid] = 0.0f;
}

__global__ void fin_k(const float* __restrict__ stats,
                      const float* __restrict__ cluster_size,
                      float* __restrict__ out_loss, float* __restrict__ out_perp,
                      float* __restrict__ out_used) {
  int tid = threadIdx.x;
  float v = 0.0f;
  float used = 0.0f;
  if (tid < 32) {
    float p = stats[1 + tid] * (1.0f / 65536.0f);
    v = p * logf(p + 1e-10f);
    used = (cluster_size[tid] > 1e-5f) ? 1.0f : 0.0f;
  }
  for (int o = 16; o; o >>= 1) { v += __shfl_down(v, o); used += __shfl_down(used, o); }
  if (tid == 0) {
    *out_perp = expf(-v);
    *out_used = used * (1.0f / 32.0f);
    *out_loss = 0.25f * stats[0] * (1.0f / 1048576.0f);
  }
}

// deconv1 (unchanged from R3): 1024 blocks.
__global__ __launch_bounds__(256) void deconv1_k(
    const float* __restrict__ q, const float* __restrict__ w,
    const float* __restrict__ bias, float* __restrict__ d1) {
  const int KD[2][2] = {{1, 3}, {0, 2}};
  const int LI[2][2] = {{1, 0}, {2, 1}};
  int idx = blockIdx.x * 256 + threadIdx.x;
  int c = idx & 31;
  int b = (idx >> 5) & 31;
  int a = (idx >> 10) & 3;
  int n = (idx >> 12) & 15;
  int cog = idx >> 16;
  float acc[2][2][2][2];
  #pragma unroll
  for (int pd = 0; pd < 2; pd++)
    #pragma unroll
    for (int ph = 0; ph < 2; ph++)
      #pragma unroll
      for (int pw = 0; pw < 2; pw++)
        #pragma unroll
        for (int co = 0; co < 2; co++) acc[pd][ph][pw][co] = bias[cog * 2 + co];
  bool vd[3], vh[3], vw[3];
  #pragma unroll
  for (int l = 0; l < 3; l++) {
    vd[l] = (unsigned)(a - 1 + l) < 4u;
    vh[l] = (unsigned)(b - 1 + l) < 32u;
    vw[l] = (unsigned)(c - 1 + l) < 32u;
  }
  #pragma unroll 1
  for (int ci = 0; ci < 16; ci++) {
    const float* ip = q + ((n * 16 + ci) * 4) * 1024;
    float in[3][3][3];
    #pragma unroll
    for (int ld = 0; ld < 3; ld++)
      #pragma unroll
      for (int lh = 0; lh < 3; lh++)
        #pragma unroll
        for (int lw = 0; lw < 3; lw++)
          in[ld][lh][lw] = (vd[ld] && vh[lh] && vw[lw])
              ? ip[(a - 1 + ld) * 1024 + (b - 1 + lh) * 32 + (c - 1 + lw)] : 0.0f;
    #pragma unroll
    for (int pd = 0; pd < 2; pd++)
      #pragma unroll
      for (int jd = 0; jd < 2; jd++) {
        int kd = KD[pd][jd], ld = LI[pd][jd];
        #pragma unroll
        for (int ph = 0; ph < 2; ph++)
          #pragma unroll
          for (int jh = 0; jh < 2; jh++) {
            int kh = KD[ph][jh], lh = LI[ph][jh];
            #pragma unroll
            for (int pw = 0; pw < 2; pw++)
              #pragma unroll
              for (int jw = 0; jw < 2; jw++) {
                int kw = KD[pw][jw], lw = LI[pw][jw];
                float iv = in[ld][lh][lw];
                #pragma unroll
                for (int co = 0; co < 2; co++)
                  acc[pd][ph][pw][co] +=
                      iv * w[((ci * 8 + cog * 2 + co) * 4 + kd) * 16 + kh * 4 + kw];
              }
          }
      }
  }
  #pragma unroll
  for (int co = 0; co < 2; co++)
    #pragma unroll
    for (int pd = 0; pd < 2; pd++)
      #pragma unroll
      for (int ph = 0; ph < 2; ph++)
        #pragma unroll
        for (int pw = 0; pw < 2; pw++)
          d1[((n * 8 + cog * 2 + co) * 8 + 2 * a + pd) * 4096 +
             (2 * b + ph) * 64 + (2 * c + pw)] = fmaxf(acc[pd][ph][pw][co], 0.0f);
}

// ============ deconv3 v4 (LDS, column-per-lane -> conflict-free) ============
// d1 (16,8,8,64,64) -> d2 (16,4,16,128,128), k4 s2 p1.
// Grid: ohtile(8) x od(16) x n(16) = 2048 blocks.
// Thread: t = tid&63 owns ow pair (2t, 2t+1); og = tid>>6 owns oh = oh0+4*og+m.
// LDS per 4-ci half: [ (cil*2+jd)*10 + lr ][72], col slot = 4+iw, slots 3/68 = 0.
__global__ __launch_bounds__(256) void deconv3_k(
    const float* __restrict__ d1, const float* __restrict__ w,
    const float* __restrict__ bias, float* __restrict__ d2) {
  __shared__ float lds[80 * 72];  // 23,040 B
  int bid = blockIdx.x;
  int tile = bid & 7;
  int od = (bid >> 3) & 15;
  int n  = bid >> 7;
  int oh0 = tile * 16;
  int tid = threadIdx.x;
  int t  = tid & 63;
  int og = tid >> 6;  // 0..3

  int kd0 = (od + 1) & 1;
  int idtop = (od + 1 - kd0) >> 1;

  float acc[4][2][4];  // [m][pw][co]
  #pragma unroll
  for (int m = 0; m < 4; m++)
    #pragma unroll
    for (int pw = 0; pw < 2; pw++)
      #pragma unroll
      for (int co = 0; co < 4; co++) acc[m][pw][co] = bias[co];

  if (tid < 80) { lds[tid * 72 + 3] = 0.0f; lds[tid * 72 + 68] = 0.0f; }

  #pragma unroll 1
  for (int half = 0; half < 2; half++) {
    __syncthreads();
    // stage 4 ci x 2 jd x 10 rows x 64 cols = 1280 float4, 5/thread
    #pragma unroll
    for (int it = 0; it < 5; it++) {
      int qq = it * 256 + tid;
      int c4 = qq & 15;
      int row = qq >> 4;           // 0..79
      int lr = row % 10;
      int jd = (row / 10) & 1;
      int cil = row / 20;
      int ci = half * 4 + cil;
      int id = idtop - jd;
      int ih = 8 * tile - 1 + lr;
      float4 v = make_float4(0.0f, 0.0f, 0.0f, 0.0f);
      if ((unsigned)id < 8u && (unsigned)ih < 64u)
        v = ld4(d1 + ((n * 8 + ci) * 8 + id) * 4096 + ih * 64 + 4 * c4);
      st4(&lds[row * 72 + 4 + 4 * c4], v);
    }
    __syncthreads();
    #pragma unroll
    for (int cil = 0; cil < 4; cil++) {
      int ci = half * 4 + cil;
      #pragma unroll
      for (int jd = 0; jd < 2; jd++) {
        const float* rb = &lds[((cil * 2 + jd) * 10 + 2 * og) * 72 + 4 + t];
        float rv[4][3];  // [rr][left,ctr,right]
        #pragma unroll
        for (int rr = 0; rr < 4; rr++) {
          rv[rr][0] = rb[rr * 72 - 1];
          rv[rr][1] = rb[rr * 72];
          rv[rr][2] = rb[rr * 72 + 1];
        }
        int kd = kd0 + 2 * jd;
        #pragma unroll
        for (int m = 0; m < 4; m++) {
          int rrh = (m >> 1) + 1 + (m & 1);
          int rrl = rrh - 1;
          int khh = (m & 1) ? 0 : 1;
          int khl = khh + 2;
          #pragma unroll
          for (int co = 0; co < 4; co++) {
            const float* wb = w + ((ci * 4 + co) * 4 + kd) * 16;
            // pw=0 (ow=2t even): kw=1 -> iw=t (ctr), kw=3 -> iw=t-1 (left)
            acc[m][0][co] += rv[rrh][1] * wb[khh * 4 + 1] + rv[rrh][0] * wb[khh * 4 + 3]
                           + rv[rrl][1] * wb[khl * 4 + 1] + rv[rrl][0] * wb[khl * 4 + 3];
            // pw=1 (ow=2t+1 odd): kw=0 -> iw=t+1 (right), kw=2 -> iw=t (ctr)
            acc[m][1][co] += rv[rrh][2] * wb[khh * 4 + 0] + rv[rrh][1] * wb[khh * 4 + 2]
                           + rv[rrl][2] * wb[khl * 4 + 0] + rv[rrl][1] * wb[khl * 4 + 2];
          }
        }
      }
    }
  }
  #pragma unroll
  for (int co = 0; co < 4; co++)
    #pragma unroll
    for (int m = 0; m < 4; m++) {
      int oh = oh0 + 4 * og + m;
      float2 o;
      o.x = fmaxf(acc[m][0][co], 0.0f);
      o.y = fmaxf(acc[m][1][co], 0.0f);
      *reinterpret_cast<float2*>(
          d2 + ((n * 4 + co) * 16 + od) * 16384 + oh * 128 + 2 * t) = o;
    }
}

// ============ deconv4 v4 (LDS, column-per-lane -> conflict-free) ============
// d2 (16,4,16,128,128) -> out (16,3,16,128,128), k3 s1 p1.
// Grid: ohtile(8) x od(16) x n(16) = 2048 blocks.
// Thread: ow = tid&127 (1 col), og = tid>>7 owns oh = oh0+8*og+m (8 rows) x 3 co.
// LDS per ci: [ld*18+lh][136], col slot = 4+iw, slots 3/132 = 0. 29,376 B.
__global__ __launch_bounds__(256) void deconv4_k(
    const float* __restrict__ d2, const float* __restrict__ w,
    const float* __restrict__ bias, float* __restrict__ out) {
  __shared__ float lds[54 * 136];  // 29,376 B
  int bid = blockIdx.x;
  int ohtile = bid & 7;
  int od = (bid >> 3) & 15;
  int n  = bid >> 7;
  int oh0 = ohtile * 16;
  int tid = threadIdx.x;
  int ow = tid & 127;
  int og = tid >> 7;  // 0..1

  float acc[8][3];
  #pragma unroll
  for (int m = 0; m < 8; m++)
    #pragma unroll
    for (int co = 0; co < 3; co++) acc[m][co] = bias[co];

  if (tid < 54) { lds[tid * 136 + 3] = 0.0f; lds[tid * 136 + 132] = 0.0f; }

  #pragma unroll 1
  for (int ci = 0; ci < 4; ci++) {
    __syncthreads();
    // stage 3 ld x 18 rows x 128 cols = 1728 float4, 7 iters (guarded)
    #pragma unroll
    for (int it = 0; it < 7; it++) {
      int qq = it * 256 + tid;
      if (qq < 1728) {
        int c4 = qq & 31;
        int row = qq >> 5;       // 0..53
        int lh = row % 18;
        int ld = row / 18;
        int id = od - 1 + ld;
        int ih = oh0 - 1 + lh;
        float4 v = make_float4(0.0f, 0.0f, 0.0f, 0.0f);
        if ((unsigned)id < 16u && (unsigned)ih < 128u)
          v = ld4(d2 + ((n * 4 + ci) * 16 + id) * 16384 + ih * 128 + 4 * c4);
        st4(&lds[row * 136 + 4 + 4 * c4], v);
      }
    }
    __syncthreads();
    #pragma unroll
    for (int ld = 0; ld < 3; ld++) {
      // rows lr = 8*og + m + lh  (m 0..7, lh 0..2); cols slot 3+ow+lw
      const float* base = &lds[(ld * 18 + 8 * og) * 136 + 3 + ow];
      float rw[3][3];
      #pragma unroll
      for (int lw = 0; lw < 3; lw++) {
        rw[0][lw] = base[lw];
        rw[1][lw] = base[136 + lw];
      }
      #pragma unroll
      for (int m = 0; m < 8; m++) {
        int i0 = m % 3, i1 = (m + 1) % 3, i2 = (m + 2) % 3;
        #pragma unroll
        for (int lw = 0; lw < 3; lw++)
          rw[i2][lw] = base[(m + 2) * 136 + lw];
        #pragma unroll
        for (int co = 0; co < 3; co++) {
          const float* wb = w + (ci * 3 + co) * 27 + (2 - ld) * 9;
          // rw[i0]: lh=0 -> kh=2 (+6); rw[i1]: kh=1 (+3); rw[i2]: kh=0 (+0)
          // cols: lw -> kw=2-lw
          acc[m][co] += rw[i0][0] * wb[6 + 2] + rw[i0][1] * wb[6 + 1] + rw[i0][2] * wb[6 + 0]
                      + rw[i1][0] * wb[3 + 2] + rw[i1][1] * wb[3 + 1] + rw[i1][2] * wb[3 + 0]
                      + rw[i2][0] * wb[2]     + rw[i2][1] * wb[1]     + rw[i2][2] * wb[0];
        }
      }
    }
  }
  #pragma unroll
  for (int co = 0; co < 3; co++)
    #pragma unroll
    for (int m = 0; m < 8; m++)
      out[((n * 3 + co) * 16 + od) * 16384 + (oh0 + 8 * og + m) * 128 + ow] =
          acc[m][co];
}

extern "C" void kernel_launch(void* const* d_in, const int* in_sizes, int n_in,
                              void* d_out, int out_size, void* d_ws, size_t ws_size,
                              hipStream_t stream) {
  const float* x      = (const float*)d_in[0];
  const float* enc_w1 = (const float*)d_in[2];
  const float* enc_b1 = (const float*)d_in[3];
  const float* enc_w2 = (const float*)d_in[4];
  const float* enc_b2 = (const float*)d_in[5];
  const float* enc_w4 = (const float*)d_in[6];
  const float* enc_b4 = (const float*)d_in[7];
  const float* dec_w1 = (const float*)d_in[8];
  const float* dec_b1 = (const float*)d_in[9];
  const float* dec_w3 = (const float*)d_in[10];
  const float* dec_b3 = (const float*)d_in[11];
  const float* dec_w4 = (const float*)d_in[12];
  const float* dec_b4 = (const float*)d_in[13];
  const float* emb    = (const float*)d_in[14];
  const float* csize  = (const float*)d_in[15];

  float* ws = (float*)d_ws;
  float* stats = ws;                      // 64
  float* quant = ws + 64;                 // 1,048,576
  float* z     = quant + 1048576;         // 1,048,576
  float* y2    = z + 1048576;             // 524,288
  float* y1    = y2 + 524288;             // 2,097,152 (dead after conv2)
  float* d1    = z;                       // 4,194,304 (reuses z/y2/y1)
  float* d2    = ws + 64 + 1048576 + 4194304;  // 16,777,216

  float* out   = (float*)d_out;                        // 12,582,912
  float* out_loss  = out + 12582912;
  float* out_codes = out_loss + 1;                     // 65,536
  float* out_perp  = out_codes + 65536;
  float* out_used  = out_perp + 1;

  init_stats_k<<<1, 64, 0, stream>>>(stats);

  conv1_k<<<512, 256, 0, stream>>>(x, enc_w1, enc_b1, y1);
  conv2_k<<<512, 256, 0, stream>>>(y1, enc_w2, enc_b2, y2);
  conv4_k<<<1024, 256, 0, stream>>>(y2, enc_w4, enc_b4, z);

  vq_k<<<256, 256, 0, stream>>>(z, emb, quant, out_codes, stats);
  fin_k<<<1, 64, 0, stream>>>(stats, csize, out_loss, out_perp, out_used);

  deconv1_k<<<1024, 256, 0, stream>>>(quant, dec_w1, dec_b1, d1);
  deconv3_k<<<2048, 256, 0, stream>>>(d1, dec_w3, dec_b3, d2);
  deconv4_k<<<2048, 256, 0, stream>>>(d2, dec_w4, dec_b4, out);
}

// Round 7
// 443.305 us; speedup vs baseline: 1.4738x; 1.4738x over previous
//
#include <hip/hip_runtime.h>
#include <math.h>

#define NB 16

// ---------------- shapes ----------------
// x:      (16, 3,16,128,128)
// y1:     (16, 4, 8, 64, 64)   conv1 k4 s2 p1 + relu
// y2:     (16, 8, 4, 32, 32)   conv2 k4 s2 p1 + relu
// z:      (16,16, 4, 32, 32)   conv4 k3 s1 p1 + clip(0,6)
// quant:  (16,16, 4, 32, 32)   VQ
// d1:     (16, 8, 8, 64, 64)   deconv1 k4 s2 p1 + relu
// d2:     (16, 4,16,128,128)   deconv3 k4 s2 p1 + relu
// out:    (16, 3,16,128,128)   deconv4 k3 s1 p1

__device__ __forceinline__ float4 ld4(const float* p) {
  return *reinterpret_cast<const float4*>(p);
}
__device__ __forceinline__ void st4(float* p, float4 v) {
  *reinterpret_cast<float4*>(p) = v;
}

// conv1 (R4 strip, measured fast): thread = 4 co x (1 od, 1 oh, 4 ow). 512 blocks.
__global__ __launch_bounds__(256) void conv1_k(
    const float* __restrict__ x, const float* __restrict__ w,
    const float* __restrict__ bias, float* __restrict__ y) {
  int idx = blockIdx.x * 256 + threadIdx.x;
  int g  = idx & 15;
  int oh = (idx >> 4) & 63;
  int od = (idx >> 10) & 7;
  int n  = idx >> 13;
  bool gl = (g > 0), gr = (g < 15);
  float acc[4][4];
  #pragma unroll
  for (int co = 0; co < 4; co++) {
    float bv = bias[co];
    #pragma unroll
    for (int m = 0; m < 4; m++) acc[co][m] = bv;
  }
  int ih0 = 2 * oh - 1;
  #pragma unroll 1
  for (int ci = 0; ci < 3; ci++) {
    #pragma unroll 1
    for (int kd = 0; kd < 4; kd++) {
      int id = 2 * od - 1 + kd;
      bool vd = (unsigned)id < 16u;
      int idc = vd ? id : 0;
      const float* plane = x + (((n * 3 + ci) * 16 + idc) * 16384);
      #pragma unroll
      for (int kh = 0; kh < 4; kh++) {
        int ih = ih0 + kh;
        bool v = vd && ((unsigned)ih < 128u);
        int ihc = (unsigned)ih < 128u ? ih : 0;
        const float* rp = plane + ihc * 128 + 8 * g;
        float r[10];
        float4 A = ld4(rp);
        float4 B = ld4(rp + 4);
        float rl = rp[-1 * (int)gl];
        float rr = rp[gr ? 8 : 0];
        r[0] = (v && gl) ? rl : 0.0f;
        r[1] = v ? A.x : 0.0f; r[2] = v ? A.y : 0.0f;
        r[3] = v ? A.z : 0.0f; r[4] = v ? A.w : 0.0f;
        r[5] = v ? B.x : 0.0f; r[6] = v ? B.y : 0.0f;
        r[7] = v ? B.z : 0.0f; r[8] = v ? B.w : 0.0f;
        r[9] = (v && gr) ? rr : 0.0f;
        #pragma unroll
        for (int co = 0; co < 4; co++) {
          const float* wb = w + ((co * 3 + ci) * 4 + kd) * 16 + kh * 4;
          #pragma unroll
          for (int kw = 0; kw < 4; kw++) {
            float wv = wb[kw];
            #pragma unroll
            for (int m = 0; m < 4; m++)
              acc[co][m] += r[2 * m + kw] * wv;
          }
        }
      }
    }
  }
  #pragma unroll
  for (int co = 0; co < 4; co++) {
    float4 o;
    o.x = fmaxf(acc[co][0], 0.0f); o.y = fmaxf(acc[co][1], 0.0f);
    o.z = fmaxf(acc[co][2], 0.0f); o.w = fmaxf(acc[co][3], 0.0f);
    st4(y + ((n * 4 + co) * 8 + od) * 4096 + oh * 64 + 4 * g, o);
  }
}

// conv2: thread = 1 pos x 4 co. 512 blocks.
__global__ __launch_bounds__(256) void conv2_k(
    const float* __restrict__ y1, const float* __restrict__ w,
    const float* __restrict__ bias, float* __restrict__ y) {
  int idx = blockIdx.x * 256 + threadIdx.x;
  int ow = idx & 31;
  int oh = (idx >> 5) & 31;
  int od = (idx >> 10) & 3;
  int n = (idx >> 12) & 15;
  int cog = idx >> 16;
  float acc[4];
  #pragma unroll
  for (int co = 0; co < 4; co++) acc[co] = bias[cog * 4 + co];
  int id0 = 2 * od - 1, ih0 = 2 * oh - 1, iw0 = 2 * ow - 1;
  bool vh[4], vw[4];
  #pragma unroll
  for (int l = 0; l < 4; l++) {
    vh[l] = (unsigned)(ih0 + l) < 64u;
    vw[l] = (unsigned)(iw0 + l) < 64u;
  }
  #pragma unroll 1
  for (int ci = 0; ci < 4; ci++) {
    const float* ip = y1 + ((n * 4 + ci) * 8) * 4096;
    #pragma unroll
    for (int kd = 0; kd < 4; kd++) {
      int id = id0 + kd;
      bool vd = (unsigned)id < 8u;
      const float* pp = ip + id * 4096;
      float p[4][4];
      #pragma unroll
      for (int kh = 0; kh < 4; kh++)
        #pragma unroll
        for (int kw = 0; kw < 4; kw++)
          p[kh][kw] = (vd && vh[kh] && vw[kw]) ? pp[(ih0 + kh) * 64 + (iw0 + kw)] : 0.0f;
      #pragma unroll
      for (int co = 0; co < 4; co++) {
        const float* wp = w + (((cog * 4 + co) * 4 + ci) * 4 + kd) * 16;
        #pragma unroll
        for (int kh = 0; kh < 4; kh++)
          #pragma unroll
          for (int kw = 0; kw < 4; kw++)
            acc[co] += p[kh][kw] * wp[kh * 4 + kw];
      }
    }
  }
  #pragma unroll
  for (int co = 0; co < 4; co++)
    y[((n * 8 + cog * 4 + co) * 4 + od) * 1024 + oh * 32 + ow] = fmaxf(acc[co], 0.0f);
}

// conv4: thread = 1 pos x 4 co. 1024 blocks.
__global__ __launch_bounds__(256) void conv4_k(
    const float* __restrict__ y2, const float* __restrict__ w,
    const float* __restrict__ bias, float* __restrict__ z) {
  int idx = blockIdx.x * 256 + threadIdx.x;
  int ow = idx & 31;
  int oh = (idx >> 5) & 31;
  int od = (idx >> 10) & 3;
  int n = (idx >> 12) & 15;
  int cog = idx >> 16;
  float acc[4];
  #pragma unroll
  for (int co = 0; co < 4; co++) acc[co] = bias[cog * 4 + co];
  bool vh[3], vw[3];
  #pragma unroll
  for (int l = 0; l < 3; l++) {
    vh[l] = (unsigned)(oh - 1 + l) < 32u;
    vw[l] = (unsigned)(ow - 1 + l) < 32u;
  }
  #pragma unroll 1
  for (int ci = 0; ci < 8; ci++) {
    const float* ip = y2 + ((n * 8 + ci) * 4) * 1024;
    #pragma unroll
    for (int kd = 0; kd < 3; kd++) {
      int id = od - 1 + kd;
      bool vd = (unsigned)id < 4u;
      const float* pp = ip + id * 1024;
      float p[3][3];
      #pragma unroll
      for (int kh = 0; kh < 3; kh++)
        #pragma unroll
        for (int kw = 0; kw < 3; kw++)
          p[kh][kw] = (vd && vh[kh] && vw[kw]) ? pp[(oh - 1 + kh) * 32 + (ow - 1 + kw)] : 0.0f;
      #pragma unroll
      for (int co = 0; co < 4; co++) {
        const float* wp = w + (((cog * 4 + co) * 8 + ci) * 3 + kd) * 9;
        #pragma unroll
        for (int kh = 0; kh < 3; kh++)
          #pragma unroll
          for (int kw = 0; kw < 3; kw++)
            acc[co] += p[kh][kw] * wp[kh * 3 + kw];
      }
    }
  }
  #pragma unroll
  for (int co = 0; co < 4; co++)
    z[((n * 16 + cog * 4 + co) * 4 + od) * 1024 + oh * 32 + ow] =
        fminf(fmaxf(acc[co], 0.0f), 6.0f);
}

// VQ (unchanged)
__global__ __launch_bounds__(256) void vq_k(
    const float* __restrict__ z, const float* __restrict__ emb,
    float* __restrict__ quant, float* __restrict__ codes_out,
    float* __restrict__ stats) {
  __shared__ float se[32 * 16];
  __shared__ float se2[32];
  __shared__ float shist[32];
  __shared__ float swred[4];
  int tid = threadIdx.x;
  for (int i = tid; i < 512; i += 256) {
    int r = i >> 4;
    float v = emb[i];
    if (r == 0) v = 0.0f;
    else if (r == 1) v = 6.0f;
    se[i] = v;
  }
  if (tid < 32) shist[tid] = 0.0f;
  __syncthreads();
  if (tid < 32) {
    float s = 0.0f;
    #pragma unroll
    for (int d = 0; d < 16; d++) { float v = se[tid * 16 + d]; s += v * v; }
    se2[tid] = s;
  }
  __syncthreads();

  int idx = blockIdx.x * 256 + tid;
  float lsum = 0.0f;
  {
    int w_ = idx & 31; int t = idx >> 5;
    int h_ = t & 31; t >>= 5;
    int d_ = t & 3;  int b_ = t >> 2;
    const float* zp = z + b_ * 65536 + d_ * 1024 + h_ * 32 + w_;
    float f[16];
    float f2 = 0.0f;
    #pragma unroll
    for (int c = 0; c < 16; c++) { float v = zp[c * 4096]; f[c] = v; f2 += v * v; }
    float best = 1e30f; int bi = 0;
    for (int e = 0; e < 32; e++) {
      float dot = 0.0f;
      #pragma unroll
      for (int c = 0; c < 16; c++) dot += f[c] * se[e * 16 + c];
      float d2 = f2 - 2.0f * dot + se2[e];
      if (d2 < best) { best = d2; bi = e; }
    }
    float* qp = quant + b_ * 65536 + d_ * 1024 + h_ * 32 + w_;
    #pragma unroll
    for (int c = 0; c < 16; c++) {
      float q = se[bi * 16 + c];
      qp[c * 4096] = q;
      float df = q - f[c];
      lsum += df * df;
    }
    codes_out[idx] = (float)bi;
    atomicAdd(&shist[bi], 1.0f);
  }
  for (int o = 32; o; o >>= 1) lsum += __shfl_down(lsum, o);
  if ((tid & 63) == 0) swred[tid >> 6] = lsum;
  __syncthreads();
  if (tid == 0) atomicAdd(&stats[0], swred[0] + swred[1] + swred[2] + swred[3]);
  if (tid < 32) {
    float h = shist[tid];
    if (h != 0.0f) atomicAdd(&stats[1 + tid], h);
  }
}

__global__ void init_stats_k(float* __restrict__ stats) {
  int tid = threadIdx.x;
  if (tid < 33) stats[tid] = 0.0f;
}

__global__ void fin_k(const float* __restrict__ stats,
                      const float* __restrict__ cluster_size,
                      float* __restrict__ out_loss, float* __restrict__ out_perp,
                      float* __restrict__ out_used) {
  int tid = threadIdx.x;
  float v = 0.0f;
  float used = 0.0f;
  if (tid < 32) {
    float p = stats[1 + tid] * (1.0f / 65536.0f);
    v = p * logf(p + 1e-10f);
    used = (cluster_size[tid] > 1e-5f) ? 1.0f : 0.0f;
  }
  for (int o = 16; o; o >>= 1) { v += __shfl_down(v, o); used += __shfl_down(used, o); }
  if (tid == 0) {
    *out_perp = expf(-v);
    *out_used = used * (1.0f / 32.0f);
    *out_loss = 0.25f * stats[0] * (1.0f / 1048576.0f);
  }
}

// deconv1 (R3, 2-co split): 1024 blocks.
__global__ __launch_bounds__(256) void deconv1_k(
    const float* __restrict__ q, const float* __restrict__ w,
    const float* __restrict__ bias, float* __restrict__ d1) {
  const int KD[2][2] = {{1, 3}, {0, 2}};
  const int LI[2][2] = {{1, 0}, {2, 1}};
  int idx = blockIdx.x * 256 + threadIdx.x;
  int c = idx & 31;
  int b = (idx >> 5) & 31;
  int a = (idx >> 10) & 3;
  int n = (idx >> 12) & 15;
  int cog = idx >> 16;
  float acc[2][2][2][2];
  #pragma unroll
  for (int pd = 0; pd < 2; pd++)
    #pragma unroll
    for (int ph = 0; ph < 2; ph++)
      #pragma unroll
      for (int pw = 0; pw < 2; pw++)
        #pragma unroll
        for (int co = 0; co < 2; co++) acc[pd][ph][pw][co] = bias[cog * 2 + co];
  bool vd[3], vh[3], vw[3];
  #pragma unroll
  for (int l = 0; l < 3; l++) {
    vd[l] = (unsigned)(a - 1 + l) < 4u;
    vh[l] = (unsigned)(b - 1 + l) < 32u;
    vw[l] = (unsigned)(c - 1 + l) < 32u;
  }
  #pragma unroll 1
  for (int ci = 0; ci < 16; ci++) {
    const float* ip = q + ((n * 16 + ci) * 4) * 1024;
    float in[3][3][3];
    #pragma unroll
    for (int ld = 0; ld < 3; ld++)
      #pragma unroll
      for (int lh = 0; lh < 3; lh++)
        #pragma unroll
        for (int lw = 0; lw < 3; lw++)
          in[ld][lh][lw] = (vd[ld] && vh[lh] && vw[lw])
              ? ip[(a - 1 + ld) * 1024 + (b - 1 + lh) * 32 + (c - 1 + lw)] : 0.0f;
    #pragma unroll
    for (int pd = 0; pd < 2; pd++)
      #pragma unroll
      for (int jd = 0; jd < 2; jd++) {
        int kd = KD[pd][jd], ld = LI[pd][jd];
        #pragma unroll
        for (int ph = 0; ph < 2; ph++)
          #pragma unroll
          for (int jh = 0; jh < 2; jh++) {
            int kh = KD[ph][jh], lh = LI[ph][jh];
            #pragma unroll
            for (int pw = 0; pw < 2; pw++)
              #pragma unroll
              for (int jw = 0; jw < 2; jw++) {
                int kw = KD[pw][jw], lw = LI[pw][jw];
                float iv = in[ld][lh][lw];
                #pragma unroll
                for (int co = 0; co < 2; co++)
                  acc[pd][ph][pw][co] +=
                      iv * w[((ci * 8 + cog * 2 + co) * 4 + kd) * 16 + kh * 4 + kw];
              }
          }
      }
  }
  #pragma unroll
  for (int co = 0; co < 2; co++)
    #pragma unroll
    for (int pd = 0; pd < 2; pd++)
      #pragma unroll
      for (int ph = 0; ph < 2; ph++)
        #pragma unroll
        for (int pw = 0; pw < 2; pw++)
          d1[((n * 8 + cog * 2 + co) * 8 + 2 * a + pd) * 4096 +
             (2 * b + ph) * 64 + (2 * c + pw)] = fmaxf(acc[pd][ph][pw][co], 0.0f);
}

// deconv3 (R2 register-cube, measured-best): thread = 2x2x2 pos x 4 co.
// 524288 threads = 2048 blocks.
__global__ __launch_bounds__(256) void deconv3_k(
    const float* __restrict__ d1, const float* __restrict__ w,
    const float* __restrict__ bias, float* __restrict__ d2) {
  const int KD[2][2] = {{1, 3}, {0, 2}};
  const int LI[2][2] = {{1, 0}, {2, 1}};
  int idx = blockIdx.x * 256 + threadIdx.x;
  int c = idx & 63;
  int b = (idx >> 6) & 63;
  int a = (idx >> 12) & 7;
  int n = idx >> 15;
  float acc[2][2][2][4];
  #pragma unroll
  for (int pd = 0; pd < 2; pd++)
    #pragma unroll
    for (int ph = 0; ph < 2; ph++)
      #pragma unroll
      for (int pw = 0; pw < 2; pw++)
        #pragma unroll
        for (int co = 0; co < 4; co++) acc[pd][ph][pw][co] = bias[co];
  bool vd[3], vh[3], vw[3];
  #pragma unroll
  for (int l = 0; l < 3; l++) {
    vd[l] = (unsigned)(a - 1 + l) < 8u;
    vh[l] = (unsigned)(b - 1 + l) < 64u;
    vw[l] = (unsigned)(c - 1 + l) < 64u;
  }
  #pragma unroll 1
  for (int ci = 0; ci < 8; ci++) {
    const float* ip = d1 + ((n * 8 + ci) * 8) * 4096;
    float in[3][3][3];
    #pragma unroll
    for (int ld = 0; ld < 3; ld++)
      #pragma unroll
      for (int lh = 0; lh < 3; lh++)
        #pragma unroll
        for (int lw = 0; lw < 3; lw++)
          in[ld][lh][lw] = (vd[ld] && vh[lh] && vw[lw])
              ? ip[(a - 1 + ld) * 4096 + (b - 1 + lh) * 64 + (c - 1 + lw)] : 0.0f;
    #pragma unroll
    for (int pd = 0; pd < 2; pd++)
      #pragma unroll
      for (int jd = 0; jd < 2; jd++) {
        int kd = KD[pd][jd], ld = LI[pd][jd];
        #pragma unroll
        for (int ph = 0; ph < 2; ph++)
          #pragma unroll
          for (int jh = 0; jh < 2; jh++) {
            int kh = KD[ph][jh], lh = LI[ph][jh];
            #pragma unroll
            for (int pw = 0; pw < 2; pw++)
              #pragma unroll
              for (int jw = 0; jw < 2; jw++) {
                int kw = KD[pw][jw], lw = LI[pw][jw];
                float iv = in[ld][lh][lw];
                #pragma unroll
                for (int co = 0; co < 4; co++)
                  acc[pd][ph][pw][co] +=
                      iv * w[((ci * 4 + co) * 4 + kd) * 16 + kh * 4 + kw];
              }
          }
      }
  }
  #pragma unroll
  for (int co = 0; co < 4; co++)
    #pragma unroll
    for (int pd = 0; pd < 2; pd++)
      #pragma unroll
      for (int ph = 0; ph < 2; ph++)
        #pragma unroll
        for (int pw = 0; pw < 2; pw++)
          d2[((n * 4 + co) * 16 + 2 * a + pd) * 16384 +
             (2 * b + ph) * 128 + (2 * c + pw)] = fmaxf(acc[pd][ph][pw][co], 0.0f);
}

// deconv4 (R2 register-patch, 79 us measured): thread = 2x2x2 pos x 3 co.
// 524288 threads = 2048 blocks.
__global__ __launch_bounds__(256) void deconv4_k(
    const float* __restrict__ d2, const float* __restrict__ w,
    const float* __restrict__ bias, float* __restrict__ out) {
  int idx = blockIdx.x * 256 + threadIdx.x;
  int c = idx & 63;
  int b = (idx >> 6) & 63;
  int a = (idx >> 12) & 7;
  int n = idx >> 15;
  float acc[2][2][2][3];
  #pragma unroll
  for (int pd = 0; pd < 2; pd++)
    #pragma unroll
    for (int ph = 0; ph < 2; ph++)
      #pragma unroll
      for (int pw = 0; pw < 2; pw++)
        #pragma unroll
        for (int co = 0; co < 3; co++) acc[pd][ph][pw][co] = bias[co];
  int ih0 = 2 * b - 1, iw0 = 2 * c - 1;
  bool vh[4], vw[4];
  #pragma unroll
  for (int l = 0; l < 4; l++) {
    vh[l] = (unsigned)(ih0 + l) < 128u;
    vw[l] = (unsigned)(iw0 + l) < 128u;
  }
  #pragma unroll 1
  for (int ci = 0; ci < 4; ci++) {
    const float* ip = d2 + ((n * 4 + ci) * 16) * 16384;
    #pragma unroll
    for (int ld = 0; ld < 4; ld++) {
      int id = 2 * a - 1 + ld;
      bool vdl = (unsigned)id < 16u;
      const float* pp = ip + id * 16384;
      float p[4][4];
      #pragma unroll
      for (int lh = 0; lh < 4; lh++)
        #pragma unroll
        for (int lw = 0; lw < 4; lw++)
          p[lh][lw] = (vdl && vh[lh] && vw[lw]) ? pp[(ih0 + lh) * 128 + (iw0 + lw)] : 0.0f;
      #pragma unroll
      for (int pd = 0; pd < 2; pd++) {
        int kd = pd + 2 - ld;
        if (kd < 0 || kd > 2) continue;
        #pragma unroll
        for (int kh = 0; kh < 3; kh++)
          #pragma unroll
          for (int kw = 0; kw < 3; kw++)
            #pragma unroll
            for (int co = 0; co < 3; co++) {
              float wv = w[(ci * 3 + co) * 27 + kd * 9 + kh * 3 + kw];
              #pragma unroll
              for (int ph = 0; ph < 2; ph++)
                #pragma unroll
                for (int pw = 0; pw < 2; pw++)
                  acc[pd][ph][pw][co] += p[ph + 2 - kh][pw + 2 - kw] * wv;
            }
      }
    }
  }
  #pragma unroll
  for (int co = 0; co < 3; co++)
    #pragma unroll
    for (int pd = 0; pd < 2; pd++)
      #pragma unroll
      for (int ph = 0; ph < 2; ph++)
        #pragma unroll
        for (int pw = 0; pw < 2; pw++)
          out[((n * 3 + co) * 16 + 2 * a + pd) * 16384 +
              (2 * b + ph) * 128 + (2 * c + pw)] = acc[pd][ph][pw][co];
}

extern "C" void kernel_launch(void* const* d_in, const int* in_sizes, int n_in,
                              void* d_out, int out_size, void* d_ws, size_t ws_size,
                              hipStream_t stream) {
  const float* x      = (const float*)d_in[0];
  const float* enc_w1 = (const float*)d_in[2];
  const float* enc_b1 = (const float*)d_in[3];
  const float* enc_w2 = (const float*)d_in[4];
  const float* enc_b2 = (const float*)d_in[5];
  const float* enc_w4 = (const float*)d_in[6];
  const float* enc_b4 = (const float*)d_in[7];
  const float* dec_w1 = (const float*)d_in[8];
  const float* dec_b1 = (const float*)d_in[9];
  const float* dec_w3 = (const float*)d_in[10];
  const float* dec_b3 = (const float*)d_in[11];
  const float* dec_w4 = (const float*)d_in[12];
  const float* dec_b4 = (const float*)d_in[13];
  const float* emb    = (const float*)d_in[14];
  const float* csize  = (const float*)d_in[15];

  float* ws = (float*)d_ws;
  float* stats = ws;                      // 64
  float* quant = ws + 64;                 // 1,048,576
  float* z     = quant + 1048576;         // 1,048,576
  float* y2    = z + 1048576;             // 524,288
  float* y1    = y2 + 524288;             // 2,097,152 (dead after conv2)
  float* d1    = z;                       // 4,194,304 (reuses z/y2/y1)
  float* d2    = ws + 64 + 1048576 + 4194304;  // 16,777,216

  float* out   = (float*)d_out;                        // 12,582,912
  float* out_loss  = out + 12582912;
  float* out_codes = out_loss + 1;                     // 65,536
  float* out_perp  = out_codes + 65536;
  float* out_used  = out_perp + 1;

  init_stats_k<<<1, 64, 0, stream>>>(stats);

  conv1_k<<<512, 256, 0, stream>>>(x, enc_w1, enc_b1, y1);
  conv2_k<<<512, 256, 0, stream>>>(y1, enc_w2, enc_b2, y2);
  conv4_k<<<1024, 256, 0, stream>>>(y2, enc_w4, enc_b4, z);

  vq_k<<<256, 256, 0, stream>>>(z, emb, quant, out_codes, stats);
  fin_k<<<1, 64, 0, stream>>>(stats, csize, out_loss, out_perp, out_used);

  deconv1_k<<<1024, 256, 0, stream>>>(quant, dec_w1, dec_b1, d1);
  deconv3_k<<<2048, 256, 0, stream>>>(d1, dec_w3, dec_b3, d2);
  deconv4_k<<<2048, 256, 0, stream>>>(d2, dec_w4, dec_b4, out);
}

// Round 8
// 384.888 us; speedup vs baseline: 1.6975x; 1.1518x over previous
//
#include <hip/hip_runtime.h>
#include <math.h>

#define NB 16

// ---------------- shapes ----------------
// x:      (16, 3,16,128,128)
// y1:     (16, 4, 8, 64, 64)   conv1 k4 s2 p1 + relu
// y2:     (16, 8, 4, 32, 32)   conv2 k4 s2 p1 + relu
// z:      (16,16, 4, 32, 32)   conv4 k3 s1 p1 + clip(0,6)
// quant:  (16,16, 4, 32, 32)   VQ
// d1:     (16, 8, 8, 64, 64)   deconv1 k4 s2 p1 + relu
// d2:     (16, 4,16,128,128)   deconv3 k4 s2 p1 + relu
// out:    (16, 3,16,128,128)   deconv4 k3 s1 p1

__device__ __forceinline__ float4 ld4(const float* p) {
  return *reinterpret_cast<const float4*>(p);
}
__device__ __forceinline__ void st4(float* p, float4 v) {
  *reinterpret_cast<float4*>(p) = v;
}

// conv1 (R4 strip, measured fast): thread = 4 co x (1 od, 1 oh, 4 ow). 512 blocks.
__global__ __launch_bounds__(256) void conv1_k(
    const float* __restrict__ x, const float* __restrict__ w,
    const float* __restrict__ bias, float* __restrict__ y) {
  int idx = blockIdx.x * 256 + threadIdx.x;
  int g  = idx & 15;
  int oh = (idx >> 4) & 63;
  int od = (idx >> 10) & 7;
  int n  = idx >> 13;
  bool gl = (g > 0), gr = (g < 15);
  float acc[4][4];
  #pragma unroll
  for (int co = 0; co < 4; co++) {
    float bv = bias[co];
    #pragma unroll
    for (int m = 0; m < 4; m++) acc[co][m] = bv;
  }
  int ih0 = 2 * oh - 1;
  #pragma unroll 1
  for (int ci = 0; ci < 3; ci++) {
    #pragma unroll 1
    for (int kd = 0; kd < 4; kd++) {
      int id = 2 * od - 1 + kd;
      bool vd = (unsigned)id < 16u;
      int idc = vd ? id : 0;
      const float* plane = x + (((n * 3 + ci) * 16 + idc) * 16384);
      #pragma unroll
      for (int kh = 0; kh < 4; kh++) {
        int ih = ih0 + kh;
        bool v = vd && ((unsigned)ih < 128u);
        int ihc = (unsigned)ih < 128u ? ih : 0;
        const float* rp = plane + ihc * 128 + 8 * g;
        float r[10];
        float4 A = ld4(rp);
        float4 B = ld4(rp + 4);
        float rl = rp[-1 * (int)gl];
        float rr = rp[gr ? 8 : 0];
        r[0] = (v && gl) ? rl : 0.0f;
        r[1] = v ? A.x : 0.0f; r[2] = v ? A.y : 0.0f;
        r[3] = v ? A.z : 0.0f; r[4] = v ? A.w : 0.0f;
        r[5] = v ? B.x : 0.0f; r[6] = v ? B.y : 0.0f;
        r[7] = v ? B.z : 0.0f; r[8] = v ? B.w : 0.0f;
        r[9] = (v && gr) ? rr : 0.0f;
        #pragma unroll
        for (int co = 0; co < 4; co++) {
          const float* wb = w + ((co * 3 + ci) * 4 + kd) * 16 + kh * 4;
          #pragma unroll
          for (int kw = 0; kw < 4; kw++) {
            float wv = wb[kw];
            #pragma unroll
            for (int m = 0; m < 4; m++)
              acc[co][m] += r[2 * m + kw] * wv;
          }
        }
      }
    }
  }
  #pragma unroll
  for (int co = 0; co < 4; co++) {
    float4 o;
    o.x = fmaxf(acc[co][0], 0.0f); o.y = fmaxf(acc[co][1], 0.0f);
    o.z = fmaxf(acc[co][2], 0.0f); o.w = fmaxf(acc[co][3], 0.0f);
    st4(y + ((n * 4 + co) * 8 + od) * 4096 + oh * 64 + 4 * g, o);
  }
}

// conv2: thread = 1 pos x 4 co. 512 blocks.
__global__ __launch_bounds__(256) void conv2_k(
    const float* __restrict__ y1, const float* __restrict__ w,
    const float* __restrict__ bias, float* __restrict__ y) {
  int idx = blockIdx.x * 256 + threadIdx.x;
  int ow = idx & 31;
  int oh = (idx >> 5) & 31;
  int od = (idx >> 10) & 3;
  int n = (idx >> 12) & 15;
  int cog = idx >> 16;
  float acc[4];
  #pragma unroll
  for (int co = 0; co < 4; co++) acc[co] = bias[cog * 4 + co];
  int id0 = 2 * od - 1, ih0 = 2 * oh - 1, iw0 = 2 * ow - 1;
  bool vh[4], vw[4];
  #pragma unroll
  for (int l = 0; l < 4; l++) {
    vh[l] = (unsigned)(ih0 + l) < 64u;
    vw[l] = (unsigned)(iw0 + l) < 64u;
  }
  #pragma unroll 1
  for (int ci = 0; ci < 4; ci++) {
    const float* ip = y1 + ((n * 4 + ci) * 8) * 4096;
    #pragma unroll
    for (int kd = 0; kd < 4; kd++) {
      int id = id0 + kd;
      bool vd = (unsigned)id < 8u;
      const float* pp = ip + id * 4096;
      float p[4][4];
      #pragma unroll
      for (int kh = 0; kh < 4; kh++)
        #pragma unroll
        for (int kw = 0; kw < 4; kw++)
          p[kh][kw] = (vd && vh[kh] && vw[kw]) ? pp[(ih0 + kh) * 64 + (iw0 + kw)] : 0.0f;
      #pragma unroll
      for (int co = 0; co < 4; co++) {
        const float* wp = w + (((cog * 4 + co) * 4 + ci) * 4 + kd) * 16;
        #pragma unroll
        for (int kh = 0; kh < 4; kh++)
          #pragma unroll
          for (int kw = 0; kw < 4; kw++)
            acc[co] += p[kh][kw] * wp[kh * 4 + kw];
      }
    }
  }
  #pragma unroll
  for (int co = 0; co < 4; co++)
    y[((n * 8 + cog * 4 + co) * 4 + od) * 1024 + oh * 32 + ow] = fmaxf(acc[co], 0.0f);
}

// conv4: thread = 1 pos x 4 co. 1024 blocks.
__global__ __launch_bounds__(256) void conv4_k(
    const float* __restrict__ y2, const float* __restrict__ w,
    const float* __restrict__ bias, float* __restrict__ z) {
  int idx = blockIdx.x * 256 + threadIdx.x;
  int ow = idx & 31;
  int oh = (idx >> 5) & 31;
  int od = (idx >> 10) & 3;
  int n = (idx >> 12) & 15;
  int cog = idx >> 16;
  float acc[4];
  #pragma unroll
  for (int co = 0; co < 4; co++) acc[co] = bias[cog * 4 + co];
  bool vh[3], vw[3];
  #pragma unroll
  for (int l = 0; l < 3; l++) {
    vh[l] = (unsigned)(oh - 1 + l) < 32u;
    vw[l] = (unsigned)(ow - 1 + l) < 32u;
  }
  #pragma unroll 1
  for (int ci = 0; ci < 8; ci++) {
    const float* ip = y2 + ((n * 8 + ci) * 4) * 1024;
    #pragma unroll
    for (int kd = 0; kd < 3; kd++) {
      int id = od - 1 + kd;
      bool vd = (unsigned)id < 4u;
      const float* pp = ip + id * 1024;
      float p[3][3];
      #pragma unroll
      for (int kh = 0; kh < 3; kh++)
        #pragma unroll
        for (int kw = 0; kw < 3; kw++)
          p[kh][kw] = (vd && vh[kh] && vw[kw]) ? pp[(oh - 1 + kh) * 32 + (ow - 1 + kw)] : 0.0f;
      #pragma unroll
      for (int co = 0; co < 4; co++) {
        const float* wp = w + (((cog * 4 + co) * 8 + ci) * 3 + kd) * 9;
        #pragma unroll
        for (int kh = 0; kh < 3; kh++)
          #pragma unroll
          for (int kw = 0; kw < 3; kw++)
            acc[co] += p[kh][kw] * wp[kh * 3 + kw];
      }
    }
  }
  #pragma unroll
  for (int co = 0; co < 4; co++)
    z[((n * 16 + cog * 4 + co) * 4 + od) * 1024 + oh * 32 + ow] =
        fminf(fmaxf(acc[co], 0.0f), 6.0f);
}

// VQ (unchanged)
__global__ __launch_bounds__(256) void vq_k(
    const float* __restrict__ z, const float* __restrict__ emb,
    float* __restrict__ quant, float* __restrict__ codes_out,
    float* __restrict__ stats) {
  __shared__ float se[32 * 16];
  __shared__ float se2[32];
  __shared__ float shist[32];
  __shared__ float swred[4];
  int tid = threadIdx.x;
  for (int i = tid; i < 512; i += 256) {
    int r = i >> 4;
    float v = emb[i];
    if (r == 0) v = 0.0f;
    else if (r == 1) v = 6.0f;
    se[i] = v;
  }
  if (tid < 32) shist[tid] = 0.0f;
  __syncthreads();
  if (tid < 32) {
    float s = 0.0f;
    #pragma unroll
    for (int d = 0; d < 16; d++) { float v = se[tid * 16 + d]; s += v * v; }
    se2[tid] = s;
  }
  __syncthreads();

  int idx = blockIdx.x * 256 + tid;
  float lsum = 0.0f;
  {
    int w_ = idx & 31; int t = idx >> 5;
    int h_ = t & 31; t >>= 5;
    int d_ = t & 3;  int b_ = t >> 2;
    const float* zp = z + b_ * 65536 + d_ * 1024 + h_ * 32 + w_;
    float f[16];
    float f2 = 0.0f;
    #pragma unroll
    for (int c = 0; c < 16; c++) { float v = zp[c * 4096]; f[c] = v; f2 += v * v; }
    float best = 1e30f; int bi = 0;
    for (int e = 0; e < 32; e++) {
      float dot = 0.0f;
      #pragma unroll
      for (int c = 0; c < 16; c++) dot += f[c] * se[e * 16 + c];
      float d2 = f2 - 2.0f * dot + se2[e];
      if (d2 < best) { best = d2; bi = e; }
    }
    float* qp = quant + b_ * 65536 + d_ * 1024 + h_ * 32 + w_;
    #pragma unroll
    for (int c = 0; c < 16; c++) {
      float q = se[bi * 16 + c];
      qp[c * 4096] = q;
      float df = q - f[c];
      lsum += df * df;
    }
    codes_out[idx] = (float)bi;
    atomicAdd(&shist[bi], 1.0f);
  }
  for (int o = 32; o; o >>= 1) lsum += __shfl_down(lsum, o);
  if ((tid & 63) == 0) swred[tid >> 6] = lsum;
  __syncthreads();
  if (tid == 0) atomicAdd(&stats[0], swred[0] + swred[1] + swred[2] + swred[3]);
  if (tid < 32) {
    float h = shist[tid];
    if (h != 0.0f) atomicAdd(&stats[1 + tid], h);
  }
}

__global__ void init_stats_k(float* __restrict__ stats) {
  int tid = threadIdx.x;
  if (tid < 33) stats[tid] = 0.0f;
}

__global__ void fin_k(const float* __restrict__ stats,
                      const float* __restrict__ cluster_size,
                      float* __restrict__ out_loss, float* __restrict__ out_perp,
                      float* __restrict__ out_used) {
  int tid = threadIdx.x;
  float v = 0.0f;
  float used = 0.0f;
  if (tid < 32) {
    float p = stats[1 + tid] * (1.0f / 65536.0f);
    v = p * logf(p + 1e-10f);
    used = (cluster_size[tid] > 1e-5f) ? 1.0f : 0.0f;
  }
  for (int o = 16; o; o >>= 1) { v += __shfl_down(v, o); used += __shfl_down(used, o); }
  if (tid == 0) {
    *out_perp = expf(-v);
    *out_used = used * (1.0f / 32.0f);
    *out_loss = 0.25f * stats[0] * (1.0f / 1048576.0f);
  }
}

// ============ deconv1 v3 (strip, deconv3-v2 structure) ============
// quant (16,16,4,32,32) -> d1 (16,8,8,64,64), k4 s2 p1.
// Grid: cog(2) x ph(2) x od(8) x n(16) = 512 blocks; block = g(8) x bl(32).
// Thread: 4 co x 8 ow (ow = 8g+m), oh = 2*bl+ph; od/ph/cog block-uniform.
__global__ __launch_bounds__(256) void deconv1_k(
    const float* __restrict__ q, const float* __restrict__ w,
    const float* __restrict__ bias, float* __restrict__ d1) {
  int bid = blockIdx.x;
  int cog = bid & 1;
  int ph  = (bid >> 1) & 1;
  int od  = (bid >> 2) & 7;
  int n   = bid >> 5;
  int tid = threadIdx.x;
  int g   = tid & 7;     // ow strip 8g..8g+7; input cols 4g-1..4g+4
  int bl  = tid >> 3;    // 0..31; oh = 2*bl + ph
  bool glf = (g > 0), grf = (g < 7);

  int kd0 = (od + 1) & 1;
  int idtop = (od + 1 - kd0) >> 1;  // id = idtop - jd, kd = kd0 + 2*jd
  int kh0 = (ph + 1) & 1;
  int ihtop = bl + ph;              // ih = ihtop - jh, kh = kh0 + 2*jh

  float acc[4][8];
  #pragma unroll
  for (int co = 0; co < 4; co++) {
    float bv = bias[cog * 4 + co];
    #pragma unroll
    for (int m = 0; m < 8; m++) acc[co][m] = bv;
  }

  #pragma unroll 1
  for (int ci = 0; ci < 16; ci++) {
    const float* ip = q + ((n * 16 + ci) * 4) * 1024;
    #pragma unroll
    for (int jd = 0; jd < 2; jd++) {
      int id = idtop - jd;
      bool vd = (unsigned)id < 4u;
      int idc = vd ? id : 0;
      const float* plane = ip + idc * 1024;
      #pragma unroll
      for (int jh = 0; jh < 2; jh++) {
        int ih = ihtop - jh;
        bool v = vd && ((unsigned)ih < 32u);
        int ihc = (unsigned)ih < 32u ? ih : 0;
        const float* rp = plane + ihc * 32 + 4 * g;
        float r[6];
        float4 A = ld4(rp);
        float rl = rp[-1 * (int)glf];
        float rr = rp[grf ? 4 : 0];
        r[0] = (v && glf) ? rl : 0.0f;
        r[1] = v ? A.x : 0.0f; r[2] = v ? A.y : 0.0f;
        r[3] = v ? A.z : 0.0f; r[4] = v ? A.w : 0.0f;
        r[5] = (v && grf) ? rr : 0.0f;
        int kd = kd0 + 2 * jd;
        int kh = kh0 + 2 * jh;
        #pragma unroll
        for (int co = 0; co < 4; co++) {
          const float* wb = w + ((ci * 8 + cog * 4 + co) * 4 + kd) * 16 + kh * 4;
          #pragma unroll
          for (int jw = 0; jw < 2; jw++) {
            float w_ev = wb[1 + 2 * jw];  // kw for even ow (pw=0)
            float w_od = wb[2 * jw];      // kw for odd  ow (pw=1)
            #pragma unroll
            for (int ii = 0; ii < 4; ii++) {
              acc[co][2 * ii]     += r[ii + 1 - jw] * w_ev;
              acc[co][2 * ii + 1] += r[ii + 2 - jw] * w_od;
            }
          }
        }
      }
    }
  }
  int oh = 2 * bl + ph;
  #pragma unroll
  for (int co = 0; co < 4; co++) {
    float* op = d1 + ((n * 8 + cog * 4 + co) * 8 + od) * 4096 + oh * 64 + 8 * g;
    float4 lo, hi;
    lo.x = fmaxf(acc[co][0], 0.0f); lo.y = fmaxf(acc[co][1], 0.0f);
    lo.z = fmaxf(acc[co][2], 0.0f); lo.w = fmaxf(acc[co][3], 0.0f);
    hi.x = fmaxf(acc[co][4], 0.0f); hi.y = fmaxf(acc[co][5], 0.0f);
    hi.z = fmaxf(acc[co][6], 0.0f); hi.w = fmaxf(acc[co][7], 0.0f);
    st4(op, lo); st4(op + 4, hi);
  }
}

// deconv3 (R2 register-cube): thread = 2x2x2 pos x 4 co. 2048 blocks.
__global__ __launch_bounds__(256) void deconv3_k(
    const float* __restrict__ d1, const float* __restrict__ w,
    const float* __restrict__ bias, float* __restrict__ d2) {
  const int KD[2][2] = {{1, 3}, {0, 2}};
  const int LI[2][2] = {{1, 0}, {2, 1}};
  int idx = blockIdx.x * 256 + threadIdx.x;
  int c = idx & 63;
  int b = (idx >> 6) & 63;
  int a = (idx >> 12) & 7;
  int n = idx >> 15;
  float acc[2][2][2][4];
  #pragma unroll
  for (int pd = 0; pd < 2; pd++)
    #pragma unroll
    for (int ph = 0; ph < 2; ph++)
      #pragma unroll
      for (int pw = 0; pw < 2; pw++)
        #pragma unroll
        for (int co = 0; co < 4; co++) acc[pd][ph][pw][co] = bias[co];
  bool vd[3], vh[3], vw[3];
  #pragma unroll
  for (int l = 0; l < 3; l++) {
    vd[l] = (unsigned)(a - 1 + l) < 8u;
    vh[l] = (unsigned)(b - 1 + l) < 64u;
    vw[l] = (unsigned)(c - 1 + l) < 64u;
  }
  #pragma unroll 1
  for (int ci = 0; ci < 8; ci++) {
    const float* ip = d1 + ((n * 8 + ci) * 8) * 4096;
    float in[3][3][3];
    #pragma unroll
    for (int ld = 0; ld < 3; ld++)
      #pragma unroll
      for (int lh = 0; lh < 3; lh++)
        #pragma unroll
        for (int lw = 0; lw < 3; lw++)
          in[ld][lh][lw] = (vd[ld] && vh[lh] && vw[lw])
              ? ip[(a - 1 + ld) * 4096 + (b - 1 + lh) * 64 + (c - 1 + lw)] : 0.0f;
    #pragma unroll
    for (int pd = 0; pd < 2; pd++)
      #pragma unroll
      for (int jd = 0; jd < 2; jd++) {
        int kd = KD[pd][jd], ld = LI[pd][jd];
        #pragma unroll
        for (int ph = 0; ph < 2; ph++)
          #pragma unroll
          for (int jh = 0; jh < 2; jh++) {
            int kh = KD[ph][jh], lh = LI[ph][jh];
            #pragma unroll
            for (int pw = 0; pw < 2; pw++)
              #pragma unroll
              for (int jw = 0; jw < 2; jw++) {
                int kw = KD[pw][jw], lw = LI[pw][jw];
                float iv = in[ld][lh][lw];
                #pragma unroll
                for (int co = 0; co < 4; co++)
                  acc[pd][ph][pw][co] +=
                      iv * w[((ci * 4 + co) * 4 + kd) * 16 + kh * 4 + kw];
              }
          }
      }
  }
  #pragma unroll
  for (int co = 0; co < 4; co++)
    #pragma unroll
    for (int pd = 0; pd < 2; pd++)
      #pragma unroll
      for (int ph = 0; ph < 2; ph++)
        #pragma unroll
        for (int pw = 0; pw < 2; pw++)
          d2[((n * 4 + co) * 16 + 2 * a + pd) * 16384 +
             (2 * b + ph) * 128 + (2 * c + pw)] = fmaxf(acc[pd][ph][pw][co], 0.0f);
}

// deconv4 (R2 register-patch): thread = 2x2x2 pos x 3 co. 2048 blocks.
__global__ __launch_bounds__(256) void deconv4_k(
    const float* __restrict__ d2, const float* __restrict__ w,
    const float* __restrict__ bias, float* __restrict__ out) {
  int idx = blockIdx.x * 256 + threadIdx.x;
  int c = idx & 63;
  int b = (idx >> 6) & 63;
  int a = (idx >> 12) & 7;
  int n = idx >> 15;
  float acc[2][2][2][3];
  #pragma unroll
  for (int pd = 0; pd < 2; pd++)
    #pragma unroll
    for (int ph = 0; ph < 2; ph++)
      #pragma unroll
      for (int pw = 0; pw < 2; pw++)
        #pragma unroll
        for (int co = 0; co < 3; co++) acc[pd][ph][pw][co] = bias[co];
  int ih0 = 2 * b - 1, iw0 = 2 * c - 1;
  bool vh[4], vw[4];
  #pragma unroll
  for (int l = 0; l < 4; l++) {
    vh[l] = (unsigned)(ih0 + l) < 128u;
    vw[l] = (unsigned)(iw0 + l) < 128u;
  }
  #pragma unroll 1
  for (int ci = 0; ci < 4; ci++) {
    const float* ip = d2 + ((n * 4 + ci) * 16) * 16384;
    #pragma unroll
    for (int ld = 0; ld < 4; ld++) {
      int id = 2 * a - 1 + ld;
      bool vdl = (unsigned)id < 16u;
      const float* pp = ip + id * 16384;
      float p[4][4];
      #pragma unroll
      for (int lh = 0; lh < 4; lh++)
        #pragma unroll
        for (int lw = 0; lw < 4; lw++)
          p[lh][lw] = (vdl && vh[lh] && vw[lw]) ? pp[(ih0 + lh) * 128 + (iw0 + lw)] : 0.0f;
      #pragma unroll
      for (int pd = 0; pd < 2; pd++) {
        int kd = pd + 2 - ld;
        if (kd < 0 || kd > 2) continue;
        #pragma unroll
        for (int kh = 0; kh < 3; kh++)
          #pragma unroll
          for (int kw = 0; kw < 3; kw++)
            #pragma unroll
            for (int co = 0; co < 3; co++) {
              float wv = w[(ci * 3 + co) * 27 + kd * 9 + kh * 3 + kw];
              #pragma unroll
              for (int ph = 0; ph < 2; ph++)
                #pragma unroll
                for (int pw = 0; pw < 2; pw++)
                  acc[pd][ph][pw][co] += p[ph + 2 - kh][pw + 2 - kw] * wv;
            }
      }
    }
  }
  #pragma unroll
  for (int co = 0; co < 3; co++)
    #pragma unroll
    for (int pd = 0; pd < 2; pd++)
      #pragma unroll
      for (int ph = 0; ph < 2; ph++)
        #pragma unroll
        for (int pw = 0; pw < 2; pw++)
          out[((n * 3 + co) * 16 + 2 * a + pd) * 16384 +
              (2 * b + ph) * 128 + (2 * c + pw)] = acc[pd][ph][pw][co];
}

extern "C" void kernel_launch(void* const* d_in, const int* in_sizes, int n_in,
                              void* d_out, int out_size, void* d_ws, size_t ws_size,
                              hipStream_t stream) {
  const float* x      = (const float*)d_in[0];
  const float* enc_w1 = (const float*)d_in[2];
  const float* enc_b1 = (const float*)d_in[3];
  const float* enc_w2 = (const float*)d_in[4];
  const float* enc_b2 = (const float*)d_in[5];
  const float* enc_w4 = (const float*)d_in[6];
  const float* enc_b4 = (const float*)d_in[7];
  const float* dec_w1 = (const float*)d_in[8];
  const float* dec_b1 = (const float*)d_in[9];
  const float* dec_w3 = (const float*)d_in[10];
  const float* dec_b3 = (const float*)d_in[11];
  const float* dec_w4 = (const float*)d_in[12];
  const float* dec_b4 = (const float*)d_in[13];
  const float* emb    = (const float*)d_in[14];
  const float* csize  = (const float*)d_in[15];

  float* ws = (float*)d_ws;
  float* stats = ws;                      // 64
  float* quant = ws + 64;                 // 1,048,576
  float* z     = quant + 1048576;         // 1,048,576
  float* y2    = z + 1048576;             // 524,288
  float* y1    = y2 + 524288;             // 2,097,152 (dead after conv2)
  float* d1    = z;                       // 4,194,304 (reuses z/y2/y1)
  float* d2    = ws + 64 + 1048576 + 4194304;  // 16,777,216

  float* out   = (float*)d_out;                        // 12,582,912
  float* out_loss  = out + 12582912;
  float* out_codes = out_loss + 1;                     // 65,536
  float* out_perp  = out_codes + 65536;
  float* out_used  = out_perp + 1;

  init_stats_k<<<1, 64, 0, stream>>>(stats);

  conv1_k<<<512, 256, 0, stream>>>(x, enc_w1, enc_b1, y1);
  conv2_k<<<512, 256, 0, stream>>>(y1, enc_w2, enc_b2, y2);
  conv4_k<<<1024, 256, 0, stream>>>(y2, enc_w4, enc_b4, z);

  vq_k<<<256, 256, 0, stream>>>(z, emb, quant, out_codes, stats);
  fin_k<<<1, 64, 0, stream>>>(stats, csize, out_loss, out_perp, out_used);

  deconv1_k<<<512, 256, 0, stream>>>(quant, dec_w1, dec_b1, d1);
  deconv3_k<<<2048, 256, 0, stream>>>(d1, dec_w3, dec_b3, d2);
  deconv4_k<<<2048, 256, 0, stream>>>(d2, dec_w4, dec_b4, out);
}